// Round 1
// baseline (35.031 us; speedup 1.0000x reference)
//
#include <hip/hip_runtime.h>

#define IN_F 128
#define OUT_F 128
#define NPB 8      // nodes per block (one per wave)
#define TJ 128     // j-tile staged in LDS
#define THREADS 512

__global__ __launch_bounds__(THREADS, 2) void sage_kernel(
    const float* __restrict__ h, const int* __restrict__ adj,
    const float* __restrict__ Ws, const float* __restrict__ bs,
    const float* __restrict__ Wn, const float* __restrict__ bn,
    const float* __restrict__ gamma, const float* __restrict__ beta,
    float* __restrict__ out, int N)
{
    __shared__ float h_tile[TJ * IN_F];     // 64 KB
    __shared__ float h_self[NPB][IN_F];     // 4 KB
    __shared__ float agg_s[NPB][IN_F];      // 4 KB
    __shared__ float out_s[NPB][OUT_F];     // 4 KB

    const int t    = threadIdx.x;
    const int w    = t >> 6;      // wave id = node-in-block
    const int lane = t & 63;

    const int base = blockIdx.x * NPB;      // first global node of block
    const int b    = base / N;              // N % NPB == 0 -> no straddle
    const int i0   = base - b * N;          // first row index in batch
    const int i    = i0 + w;                // this wave's row
    const int gnode = base + w;

    const float* hb     = h + (size_t)b * N * IN_F;
    const int*   adjrow = adj + (size_t)b * N * N + (size_t)i * N;

    // stage this block's own h rows (for self GEMM / no-neighbor fallback)
    for (int idx = t; idx < NPB * IN_F; idx += THREADS)
        h_self[idx / IN_F][idx % IN_F] = hb[(size_t)i0 * IN_F + idx];

    // ---------------- max aggregation ----------------
    float a0 = -1e30f, a1 = -1e30f;
    unsigned long long any = 0ull;

    for (int jt = 0; jt < N; jt += TJ) {
        __syncthreads();   // previous tile fully consumed
        // cooperative stage h[b, jt:jt+TJ, :] -> LDS (contiguous, float4)
        {
            const float4* src = (const float4*)(hb + (size_t)jt * IN_F);
            float4* dst = (float4*)h_tile;
            #pragma unroll
            for (int k = 0; k < (TJ * IN_F / 4) / THREADS; ++k)
                dst[t + k * THREADS] = src[t + k * THREADS];
        }
        __syncthreads();

        const int j1 = jt + lane;
        const int j2 = jt + 64 + lane;
        unsigned long long m0 = __ballot(adjrow[j1] != 0 && j1 != i);
        unsigned long long m1 = __ballot(adjrow[j2] != 0 && j2 != i);
        any |= (m0 | m1);

        // iterate set bits, 4 LDS reads in flight
        auto scan = [&](unsigned long long m, const float* bas) {
            int cnt = __popcll(m);
            while (cnt >= 4) {
                int r0 = __builtin_ctzll(m); m &= m - 1;
                int r1 = __builtin_ctzll(m); m &= m - 1;
                int r2 = __builtin_ctzll(m); m &= m - 1;
                int r3 = __builtin_ctzll(m); m &= m - 1;
                float2 v0 = *(const float2*)&bas[r0 * IN_F + 2 * lane];
                float2 v1 = *(const float2*)&bas[r1 * IN_F + 2 * lane];
                float2 v2 = *(const float2*)&bas[r2 * IN_F + 2 * lane];
                float2 v3 = *(const float2*)&bas[r3 * IN_F + 2 * lane];
                a0 = fmaxf(a0, fmaxf(fmaxf(v0.x, v1.x), fmaxf(v2.x, v3.x)));
                a1 = fmaxf(a1, fmaxf(fmaxf(v0.y, v1.y), fmaxf(v2.y, v3.y)));
                cnt -= 4;
            }
            while (m) {
                int r = __builtin_ctzll(m); m &= m - 1;
                float2 v = *(const float2*)&bas[r * IN_F + 2 * lane];
                a0 = fmaxf(a0, v.x);
                a1 = fmaxf(a1, v.y);
            }
        };
        scan(m0, &h_tile[0]);
        scan(m1, &h_tile[64 * IN_F]);
    }

    if (!any) {   // no neighbors -> fall back to own features
        a0 = h_self[w][2 * lane];
        a1 = h_self[w][2 * lane + 1];
    }
    agg_s[w][2 * lane]     = a0;
    agg_s[w][2 * lane + 1] = a1;
    __syncthreads();

    // ---------------- GEMMs + bias ----------------
    // thread t -> output o = t&127, node pair p = t>>7 handling nodes 2p, 2p+1
    const int o  = t & (OUT_F - 1);
    const int p  = t >> 7;
    const int n0 = 2 * p, n1 = 2 * p + 1;
    float acc0 = bs[o] + bn[o];
    float acc1 = acc0;
    #pragma unroll 4
    for (int f = 0; f < IN_F; ++f) {
        const float ws = Ws[f * OUT_F + o];
        const float wn = Wn[f * OUT_F + o];
        acc0 = fmaf(h_self[n0][f], ws, acc0);
        acc0 = fmaf(agg_s[n0][f], wn, acc0);
        acc1 = fmaf(h_self[n1][f], ws, acc1);
        acc1 = fmaf(agg_s[n1][f], wn, acc1);
    }
    out_s[n0][o] = acc0;
    out_s[n1][o] = acc1;
    __syncthreads();

    // ---------------- LayerNorm + ReLU ----------------
    // wave w normalizes node w; lane covers outputs {lane, lane+64}
    const float x0 = out_s[w][lane];
    const float x1 = out_s[w][lane + 64];
    float s  = x0 + x1;
    float s2 = x0 * x0 + x1 * x1;
    #pragma unroll
    for (int d = 32; d >= 1; d >>= 1) {
        s  += __shfl_xor(s, d, 64);
        s2 += __shfl_xor(s2, d, 64);
    }
    const float mu  = s * (1.0f / OUT_F);
    const float var = s2 * (1.0f / OUT_F) - mu * mu;
    const float rs  = rsqrtf(var + 1e-5f);

    float* orow = out + (size_t)gnode * OUT_F;
    const float r0 = (x0 - mu) * rs * gamma[lane]      + beta[lane];
    const float r1 = (x1 - mu) * rs * gamma[lane + 64] + beta[lane + 64];
    orow[lane]      = fmaxf(r0, 0.0f);
    orow[lane + 64] = fmaxf(r1, 0.0f);
}

extern "C" void kernel_launch(void* const* d_in, const int* in_sizes, int n_in,
                              void* d_out, int out_size, void* d_ws, size_t ws_size,
                              hipStream_t stream) {
    const float* h     = (const float*)d_in[0];
    const int*   adj   = (const int*)d_in[1];
    const float* Ws    = (const float*)d_in[2];
    const float* bs    = (const float*)d_in[3];
    const float* Wn    = (const float*)d_in[4];
    const float* bn    = (const float*)d_in[5];
    const float* gamma = (const float*)d_in[6];
    const float* beta  = (const float*)d_in[7];
    float* out = (float*)d_out;

    const long long bn_nodes = in_sizes[0] / IN_F;          // B*N
    const int N = (int)((long long)in_sizes[1] / bn_nodes); // adj is B*N*N
    const int grid = (int)(bn_nodes / NPB);

    hipLaunchKernelGGL(sage_kernel, dim3(grid), dim3(THREADS), 0, stream,
                       h, adj, Ws, bs, Wn, bn, gamma, beta, out, N);
}

// Round 2
// 34.513 us; speedup vs baseline: 1.0150x; 1.0150x over previous
//
#include <hip/hip_runtime.h>
#include <cstdint>

#define IN_F 128
#define OUT_F 128
#define NPB 8      // nodes per block
#define THREADS 512
#define NEG_BIG -1e30f

__global__ __launch_bounds__(THREADS, 2) void sage_kernel(
    const float* __restrict__ h, const int* __restrict__ adj,
    const float* __restrict__ Ws, const float* __restrict__ bs,
    const float* __restrict__ Wn, const float* __restrict__ bn,
    const float* __restrict__ gamma, const float* __restrict__ beta,
    float* __restrict__ out, int N)
{
    __shared__ float part[NPB][NPB][IN_F];   // [wave][node][feat] 32 KB
    __shared__ unsigned anyw_s[NPB];
    __shared__ float h_self[NPB][IN_F];      // 4 KB
    __shared__ float agg_s[NPB][IN_F];       // 4 KB
    __shared__ float out_s[NPB][OUT_F];      // 4 KB

    const int t    = threadIdx.x;
    const int w    = t >> 6;       // wave id = j-strip owner
    const int lane = t & 63;

    const int base = blockIdx.x * NPB;   // first global node of block
    const int b    = base / N;
    const int i0   = base - b * N;
    const int gnode = base + w;

    const float* hb   = h + (size_t)b * N * IN_F;
    const int*   adjb = adj + (size_t)b * N * N;

    const int jrange = N / NPB;          // 128
    const int jbase  = w * jrange;

    // ---- per-wave masks for all 8 nodes over this wave's j-range ----
    unsigned long long mlo[NPB], mhi[NPB];
    unsigned anybits = 0;
    #pragma unroll
    for (int n = 0; n < NPB; ++n) {
        const int i_n = i0 + n;
        const int* ar = adjb + (size_t)i_n * N;
        const int j1 = jbase + lane;
        const int j2 = jbase + 64 + lane;
        mlo[n] = __ballot(ar[j1] != 0 && j1 != i_n);
        mhi[n] = __ballot(ar[j2] != 0 && j2 != i_n);
        anybits |= ((mlo[n] | mhi[n]) != 0ull ? 1u : 0u) << n;
    }

    // ---- dense masked-max scan over this wave's 128 j's ----
    float2 a[NPB];
    #pragma unroll
    for (int n = 0; n < NPB; ++n) { a[n].x = NEG_BIG; a[n].y = NEG_BIG; }

    const float* hrow = hb + (size_t)jbase * IN_F + 2 * lane;
    const float PINF = __builtin_inff();

    #pragma unroll 4
    for (int k = 0; k < 64; ++k) {
        const float2 v = *(const float2*)(hrow + (size_t)k * IN_F);
        #pragma unroll
        for (int n = 0; n < NPB; ++n) {
            const bool sel = (mlo[n] >> k) & 1ull;       // wave-uniform
            const float cap = sel ? PINF : -PINF;        // s_cselect
            a[n].x = fmaxf(a[n].x, fminf(v.x, cap));
            a[n].y = fmaxf(a[n].y, fminf(v.y, cap));
        }
    }
    #pragma unroll 4
    for (int k = 0; k < 64; ++k) {
        const float2 v = *(const float2*)(hrow + (size_t)(k + 64) * IN_F);
        #pragma unroll
        for (int n = 0; n < NPB; ++n) {
            const bool sel = (mhi[n] >> k) & 1ull;
            const float cap = sel ? PINF : -PINF;
            a[n].x = fmaxf(a[n].x, fminf(v.x, cap));
            a[n].y = fmaxf(a[n].y, fminf(v.y, cap));
        }
    }

    // ---- publish partials, combine across waves ----
    #pragma unroll
    for (int n = 0; n < NPB; ++n) {
        part[w][n][2 * lane]     = a[n].x;
        part[w][n][2 * lane + 1] = a[n].y;
    }
    if (lane == 0) anyw_s[w] = anybits;
    __syncthreads();

    // wave w now reduces node w; lane covers features {2l, 2l+1}
    float rx = NEG_BIG, ry = NEG_BIG;
    #pragma unroll
    for (int wp = 0; wp < NPB; ++wp) {
        const float2 p = *(const float2*)&part[wp][w][2 * lane];
        rx = fmaxf(rx, p.x);
        ry = fmaxf(ry, p.y);
    }
    unsigned anyall = 0;
    #pragma unroll
    for (int wp = 0; wp < NPB; ++wp) anyall |= anyw_s[wp];
    const bool has = (anyall >> w) & 1u;

    const float2 hs = *(const float2*)&hb[(size_t)(i0 + w) * IN_F + 2 * lane];
    if (!has) { rx = hs.x; ry = hs.y; }

    h_self[w][2 * lane]     = hs.x;
    h_self[w][2 * lane + 1] = hs.y;
    agg_s[w][2 * lane]      = rx;
    agg_s[w][2 * lane + 1]  = ry;
    __syncthreads();

    // ---------------- GEMMs + bias ----------------
    const int o  = t & (OUT_F - 1);
    const int p  = t >> 7;
    const int n0 = 2 * p, n1 = 2 * p + 1;
    float acc0 = bs[o] + bn[o];
    float acc1 = acc0;
    #pragma unroll 4
    for (int f = 0; f < IN_F; ++f) {
        const float ws = Ws[f * OUT_F + o];
        const float wn = Wn[f * OUT_F + o];
        acc0 = fmaf(h_self[n0][f], ws, acc0);
        acc0 = fmaf(agg_s[n0][f], wn, acc0);
        acc1 = fmaf(h_self[n1][f], ws, acc1);
        acc1 = fmaf(agg_s[n1][f], wn, acc1);
    }
    out_s[n0][o] = acc0;
    out_s[n1][o] = acc1;
    __syncthreads();

    // ---------------- LayerNorm + ReLU ----------------
    const float x0 = out_s[w][lane];
    const float x1 = out_s[w][lane + 64];
    float s  = x0 + x1;
    float s2 = x0 * x0 + x1 * x1;
    #pragma unroll
    for (int d = 32; d >= 1; d >>= 1) {
        s  += __shfl_xor(s, d, 64);
        s2 += __shfl_xor(s2, d, 64);
    }
    const float mu  = s * (1.0f / OUT_F);
    const float var = s2 * (1.0f / OUT_F) - mu * mu;
    const float rs  = rsqrtf(var + 1e-5f);

    float* orow = out + (size_t)gnode * OUT_F;
    const float r0 = (x0 - mu) * rs * gamma[lane]      + beta[lane];
    const float r1 = (x1 - mu) * rs * gamma[lane + 64] + beta[lane + 64];
    orow[lane]      = fmaxf(r0, 0.0f);
    orow[lane + 64] = fmaxf(r1, 0.0f);
}

extern "C" void kernel_launch(void* const* d_in, const int* in_sizes, int n_in,
                              void* d_out, int out_size, void* d_ws, size_t ws_size,
                              hipStream_t stream) {
    const float* h     = (const float*)d_in[0];
    const int*   adj   = (const int*)d_in[1];
    const float* Ws    = (const float*)d_in[2];
    const float* bs    = (const float*)d_in[3];
    const float* Wn    = (const float*)d_in[4];
    const float* bn    = (const float*)d_in[5];
    const float* gamma = (const float*)d_in[6];
    const float* beta  = (const float*)d_in[7];
    float* out = (float*)d_out;

    const long long bn_nodes = in_sizes[0] / IN_F;          // B*N
    const int N = (int)((long long)in_sizes[1] / bn_nodes); // adj is B*N*N
    const int grid = (int)(bn_nodes / NPB);

    hipLaunchKernelGGL(sage_kernel, dim3(grid), dim3(THREADS), 0, stream,
                       h, adj, Ws, bs, Wn, bn, gamma, beta, out, N);
}

// Round 3
// 34.509 us; speedup vs baseline: 1.0151x; 1.0001x over previous
//
#include <hip/hip_runtime.h>
#include <cstdint>

#define IN_F 128
#define OUT_F 128
#define NPB 8       // nodes per block
#define WAVES 16
#define THREADS 1024
#define STRIP 64    // j-columns per wave (N / WAVES)
#define NEG_BIG -1e30f

__global__ __launch_bounds__(THREADS, 4) void sage_kernel(
    const float* __restrict__ h, const int* __restrict__ adj,
    const float* __restrict__ Ws, const float* __restrict__ bs,
    const float* __restrict__ Wn, const float* __restrict__ bn,
    const float* __restrict__ gamma, const float* __restrict__ beta,
    float* __restrict__ out, int N)
{
    __shared__ float part[WAVES][NPB][IN_F];   // 64 KB
    __shared__ unsigned anyw_s[WAVES];
    __shared__ float h_self[NPB][IN_F];        // 4 KB
    __shared__ float agg_s[NPB][IN_F];         // 4 KB
    __shared__ float out_s[NPB][OUT_F];        // 4 KB

    const int t    = threadIdx.x;
    const int w    = t >> 6;
    const int lane = t & 63;

    const int base = blockIdx.x * NPB;
    const int b    = base / N;
    const int i0   = base - b * N;

    const float* hb   = h + (size_t)b * N * IN_F;
    const int*   adjb = adj + (size_t)b * N * N;
    const int jbase   = w * STRIP;

    // ---- one 64-bit mask per node over this wave's 64-column strip ----
    unsigned long long m[NPB];
    unsigned anybits = 0;
    #pragma unroll
    for (int n = 0; n < NPB; ++n) {
        const int i_n = i0 + n;
        const int j   = jbase + lane;
        m[n] = __ballot(adjb[(size_t)i_n * N + j] != 0 && j != i_n);
        anybits |= (m[n] != 0ull ? 1u : 0u) << n;
    }

    // ---- dense masked-max scan, 2 k's per iteration (min/min/max3) ----
    float ax[NPB], ay[NPB];
    #pragma unroll
    for (int n = 0; n < NPB; ++n) { ax[n] = NEG_BIG; ay[n] = NEG_BIG; }

    const float* hrow = hb + (size_t)jbase * IN_F + 2 * lane;
    const float PINF = __builtin_inff();

    #pragma unroll 4
    for (int kk = 0; kk < STRIP / 2; ++kk) {
        const float2 v0 = *(const float2*)(hrow + (size_t)(2 * kk)     * IN_F);
        const float2 v1 = *(const float2*)(hrow + (size_t)(2 * kk + 1) * IN_F);
        #pragma unroll
        for (int n = 0; n < NPB; ++n) {
            const float c0 = ((m[n] >> (2 * kk))     & 1ull) ? PINF : -PINF;  // s_cselect
            const float c1 = ((m[n] >> (2 * kk + 1)) & 1ull) ? PINF : -PINF;
            ax[n] = fmaxf(fmaxf(fminf(v0.x, c0), fminf(v1.x, c1)), ax[n]);    // -> v_max3
            ay[n] = fmaxf(fmaxf(fminf(v0.y, c0), fminf(v1.y, c1)), ay[n]);
        }
    }

    #pragma unroll
    for (int n = 0; n < NPB; ++n)
        *(float2*)&part[w][n][2 * lane] = make_float2(ax[n], ay[n]);
    if (lane == 0) anyw_s[w] = anybits;
    __syncthreads();

    // ---- combine partials (waves 0-7) / stage h_self (waves 8-15) ----
    if (w < NPB) {
        float rx = NEG_BIG, ry = NEG_BIG;
        #pragma unroll
        for (int wp = 0; wp < WAVES; ++wp) {
            const float2 p = *(const float2*)&part[wp][w][2 * lane];
            rx = fmaxf(rx, p.x);
            ry = fmaxf(ry, p.y);
        }
        unsigned anyall = 0;
        #pragma unroll
        for (int wp = 0; wp < WAVES; ++wp) anyall |= anyw_s[wp];
        const float2 hs = *(const float2*)&hb[(size_t)(i0 + w) * IN_F + 2 * lane];
        if (!((anyall >> w) & 1u)) { rx = hs.x; ry = hs.y; }
        *(float2*)&agg_s[w][2 * lane] = make_float2(rx, ry);
    } else {
        const int n2 = w - NPB;
        const float2 hs = *(const float2*)&hb[(size_t)(i0 + n2) * IN_F + 2 * lane];
        *(float2*)&h_self[n2][2 * lane] = hs;
    }
    __syncthreads();

    // ---- GEMMs + bias: thread -> (node = t>>7, o = t&127) ----
    const int o    = t & (OUT_F - 1);
    const int node = t >> 7;
    float acc = bs[o] + bn[o];
    #pragma unroll 8
    for (int f = 0; f < IN_F; ++f) {
        acc = fmaf(h_self[node][f], Ws[f * OUT_F + o], acc);  // LDS broadcast reads
        acc = fmaf(agg_s[node][f],  Wn[f * OUT_F + o], acc);
    }
    out_s[node][o] = acc;
    __syncthreads();

    // ---- LayerNorm + ReLU (waves 0-7, node w) ----
    if (w < NPB) {
        const float x0 = out_s[w][lane];
        const float x1 = out_s[w][lane + 64];
        float s  = x0 + x1;
        float s2 = x0 * x0 + x1 * x1;
        #pragma unroll
        for (int d = 32; d >= 1; d >>= 1) {
            s  += __shfl_xor(s, d, 64);
            s2 += __shfl_xor(s2, d, 64);
        }
        const float mu  = s * (1.0f / OUT_F);
        const float var = s2 * (1.0f / OUT_F) - mu * mu;
        const float rs  = rsqrtf(var + 1e-5f);

        float* orow = out + (size_t)(base + w) * OUT_F;
        const float r0 = (x0 - mu) * rs * gamma[lane]      + beta[lane];
        const float r1 = (x1 - mu) * rs * gamma[lane + 64] + beta[lane + 64];
        orow[lane]      = fmaxf(r0, 0.0f);
        orow[lane + 64] = fmaxf(r1, 0.0f);
    }
}

extern "C" void kernel_launch(void* const* d_in, const int* in_sizes, int n_in,
                              void* d_out, int out_size, void* d_ws, size_t ws_size,
                              hipStream_t stream) {
    const float* h     = (const float*)d_in[0];
    const int*   adj   = (const int*)d_in[1];
    const float* Ws    = (const float*)d_in[2];
    const float* bs    = (const float*)d_in[3];
    const float* Wn    = (const float*)d_in[4];
    const float* bn    = (const float*)d_in[5];
    const float* gamma = (const float*)d_in[6];
    const float* beta  = (const float*)d_in[7];
    float* out = (float*)d_out;

    const long long bn_nodes = in_sizes[0] / IN_F;          // B*N
    const int N = (int)((long long)in_sizes[1] / bn_nodes); // adj is B*N*N
    const int grid = (int)(bn_nodes / NPB);

    hipLaunchKernelGGL(sage_kernel, dim3(grid), dim3(THREADS), 0, stream,
                       h, adj, Ws, bs, Wn, bn, gamma, beta, out, N);
}